// Round 12
// baseline (700.962 us; speedup 1.0000x reference)
//
#include <hip/hip_runtime.h>

typedef float f32x2 __attribute__((ext_vector_type(2)));
typedef float f32x4 __attribute__((ext_vector_type(4)));

#define BB 128   // 128 blocks x 2 batches each
#define TT 1024
#define HH 128
#define CC 2

// 2*log2(e): weights/bias pre-scaled so tanh needs no argument scaling.
#define LOG2E2 2.885390081777927f

// tanh(u) = 1 - 2/(exp2(u2)+1), u2 = 2*log2e*u (scale folded into weights).
__device__ __forceinline__ float ftanh2(float u2) {
    float e = __builtin_amdgcn_exp2f(u2);
    float r = __builtin_amdgcn_rcpf(e + 1.0f);
    return fmaf(-2.0f, r, 1.0f);
}

// broadcast lane j's value to all lanes via SGPR (VALU pipe, no LDS)
__device__ __forceinline__ float bcast(float v, int j) {
    return __int_as_float(__builtin_amdgcn_readlane(__float_as_int(v), j));
}

// v + cross-lane(v) via DPP: VALU pipe, no LDS.
#define DPP_ADD(v, ctrl)                                                     \
    ((v) + __int_as_float(__builtin_amdgcn_mov_dpp(                          \
         __float_as_int(v), (ctrl), 0xF, 0xF, true)))

// Loop barrier: LDS-only drain (the every-16-step output stores need no
// ordering vs the barrier -> skip the vmcnt(0) drain of __syncthreads).
#define SYNC() asm volatile("s_waitcnt lgkmcnt(0)\n\ts_barrier" ::: "memory")

// R10: R0's proven 4-wave k-quarter structure, TWO batches per block.
// R0-R9 established: step = ~384cyc/wave issue + ~550cyc cross-wave chain
// (ship->barrier->read->tanh latency). More waves shrink issue but grow the
// chain (R6); one wave kills the chain but doubles issue (R9). Two batches
// share the weights (no extra VGPR/L1 cost) and each batch's combine chain
// hides under the OTHER batch's matvec/logit issue -> wall/step ~650cyc for
// 2 batches vs 937 for 1.
__global__ __launch_bounds__(256, 1) void rnn_kernel(
    const float* __restrict__ x, const float* __restrict__ W_ih,
    const float* __restrict__ W_hh, const float* __restrict__ b_ih,
    const float* __restrict__ b_hh, const float* __restrict__ W_fc,
    const float* __restrict__ b_fc, float* __restrict__ out)
{
    const int b0  = blockIdx.x * 2;     // batches b0, b0+1
    const int tid = threadIdx.x;        // 0..255
    const int l   = tid & 63;
    const int wv  = tid >> 6;           // 0..3
    const int lq  = l & 31;
    const int kb  = wv << 5;            // this wave's k-quarter base
    const int rA  = l, rB = l + 64;     // partial rows this lane computes
    const int rF  = kb + lq;            // row this wave finalizes (dup lanes 32..63)

    __shared__ float xs[2][TT + 8];     // input sequences (+pad for prefetch)
    __shared__ f32x2 p2[2][2][4][64];   // [buf][batch][src wave][lane] = {pA,pB}
    __shared__ f32x2 qp[4][2][4];       // [t&3][batch][wave] logit partials
    __shared__ f32x2 obuf[2][16];       // batched output rings (wave 0 only)

    // preload both x rows (256 lanes x f32x4 each, coalesced)
    {
        const f32x4* xr0 = (const f32x4*)(x + (size_t)b0 * TT);
        const f32x4* xr1 = (const f32x4*)(x + (size_t)(b0 + 1) * TT);
        ((f32x4*)xs[0])[tid] = xr0[tid];
        ((f32x4*)xs[1])[tid] = xr1[tid];
    }
    if (tid < 8) { xs[0][TT + tid] = 0.f; xs[1][TT + tid] = 0.f; }

    const float wih  = W_ih[rF] * LOG2E2;
    const float bias = (b_ih[rF] + b_hh[rF]) * LOG2E2;
    // split-class: lanes 0..31 carry class 0, lanes 32..63 (dup rows) class 1
    const float wfs  = (l < 32) ? W_fc[rF] : W_fc[HH + rF];
    const float bf0  = b_fc[0], bf1 = b_fc[1];

    // per-lane weights: rows rA,rB over k in [kb,kb+32), pre-scaled by 2log2e.
    // Shared by BOTH batches. Compiler re-fetches from L1 per step (R5 proved
    // that refetch is latency-hidden; do not pin).
    float wa[32], wb[32];
    {
        const f32x4* a4 = (const f32x4*)(W_hh + (size_t)rA * HH + kb);
        const f32x4* b4 = (const f32x4*)(W_hh + (size_t)rB * HH + kb);
        #pragma unroll
        for (int j = 0; j < 8; ++j) {
            f32x4 va = a4[j], vb = b4[j];
            wa[4*j+0] = va.x * LOG2E2; wa[4*j+1] = va.y * LOG2E2;
            wa[4*j+2] = va.z * LOG2E2; wa[4*j+3] = va.w * LOG2E2;
            wb[4*j+0] = vb.x * LOG2E2; wb[4*j+1] = vb.y * LOG2E2;
            wb[4*j+2] = vb.z * LOG2E2; wb[4*j+3] = vb.w * LOG2E2;
        }
        #pragma unroll
        for (int k = 0; k < 32; ++k)
            asm volatile("" : "+v"(wa[k]), "+v"(wb[k]));
    }

    float hn0 = 0.f, hn1 = 0.f;         // h_t[rF] for batch 0 / batch 1
    float* o0 = out + (size_t)b0 * TT * CC;
    float* o1 = out + (size_t)(b0 + 1) * TT * CC;

    __syncthreads();                    // xs visible (one-time, full drain)
    float xc0 = xs[0][0], xc1 = xs[1][0];

    #pragma unroll 2
    for (int t = 0; t < TT; ++t) {
        const int buf = t & 1, qb = t & 3;

        // ---- pre-barrier: partial matvec for batch 0, then batch 1.
        // b1's matvec is independent issue that lands in b0's ship window.
        {
            float aA0 = 0.f, aA1 = 0.f, aB0 = 0.f, aB1 = 0.f;
            #pragma unroll
            for (int k = 0; k < 32; k += 2) {
                float s0 = bcast(hn0, k);
                float s1 = bcast(hn0, k + 1);
                aA0 = fmaf(wa[k],     s0, aA0);
                aB0 = fmaf(wb[k],     s0, aB0);
                aA1 = fmaf(wa[k + 1], s1, aA1);
                aB1 = fmaf(wb[k + 1], s1, aB1);
            }
            p2[buf][0][wv][l] = f32x2{ aA0 + aA1, aB0 + aB1 };
        }
        {
            float cA0 = 0.f, cA1 = 0.f, cB0 = 0.f, cB1 = 0.f;
            #pragma unroll
            for (int k = 0; k < 32; k += 2) {
                float s0 = bcast(hn1, k);
                float s1 = bcast(hn1, k + 1);
                cA0 = fmaf(wa[k],     s0, cA0);
                cB0 = fmaf(wb[k],     s0, cB0);
                cA1 = fmaf(wa[k + 1], s1, cA1);
                cB1 = fmaf(wb[k + 1], s1, cB1);
            }
            p2[buf][1][wv][l] = f32x2{ cA0 + cA1, cB0 + cB1 };
        }
        const float xn0 = xs[0][t + 1];   // prefetch (fire-and-forget)
        const float xn1 = xs[1][t + 1];

        SYNC();                           // the single per-step barrier

        // ---- post-barrier: issue all 8 combine reads, fill their ~120-cyc
        // latency shadow with both logit trees + output bookkeeping.
        const int fofs = ((((wv & 1) << 5) + lq) << 1) + (wv >> 1);
        const float* pf0 = (const float*)&p2[buf][0][0][0] + fofs;
        const float* pf1 = (const float*)&p2[buf][1][0][0] + fofs;
        float p00 = pf0[0], p01 = pf0[128], p02 = pf0[256], p03 = pf0[384];
        float p10 = pf1[0], p11 = pf1[128], p12 = pf1[256], p13 = pf1[384];

        {   // logits of h_t (batch 0): split-class DPP reduce
            float q = wfs * hn0;
            q = DPP_ADD(q, 0xB1);
            q = DPP_ADD(q, 0x4E);
            q = DPP_ADD(q, 0x124);
            q = DPP_ADD(q, 0x128);
            float q0 = bcast(q, 0)  + bcast(q, 16);
            float q1 = bcast(q, 32) + bcast(q, 48);
            if (l == 0) qp[qb][0][wv] = f32x2{q0, q1};
        }
        {   // logits of h_t (batch 1)
            float q = wfs * hn1;
            q = DPP_ADD(q, 0xB1);
            q = DPP_ADD(q, 0x4E);
            q = DPP_ADD(q, 0x124);
            q = DPP_ADD(q, 0x128);
            float q0 = bcast(q, 0)  + bcast(q, 16);
            float q1 = bcast(q, 32) + bcast(q, 48);
            if (l == 0) qp[qb][1][wv] = f32x2{q0, q1};
        }
        // out[t-2] entries (both batches): qp[(t-1)&3] = logits(h_{t-1})
        if (t >= 2 && tid == 0) {
            const int pq = (t - 1) & 3;
            f32x2 s0 = (qp[pq][0][0] + qp[pq][0][1]) + (qp[pq][0][2] + qp[pq][0][3]);
            s0.x += bf0; s0.y += bf1;
            obuf[0][(t - 2) & 15] = s0;
            f32x2 s1 = (qp[pq][1][0] + qp[pq][1][1]) + (qp[pq][1][2] + qp[pq][1][3]);
            s1.x += bf0; s1.y += bf1;
            obuf[1][(t - 2) & 15] = s1;
        }
        // flush both 16-entry windows every 16 steps (wave 0: lanes 0-31 b0,
        // lanes 32-63 b1; same-wave LDS ordering vs obuf writes above)
        if ((t & 15) == 1 && t >= 17 && tid < 64) {
            const int bb = tid >> 5, ln = tid & 31;
            float* oo = bb ? o1 : o0;
            ((float*)(oo + (t - 17) * CC))[ln] = ((const float*)obuf[bb])[ln];
        }

        const float base0 = fmaf(xc0, wih, bias);
        const float base1 = fmaf(xc1, wih, bias);
        xc0 = xn0; xc1 = xn1;
        // combines arrive here, shadows filled:
        hn0 = ftanh2(base0 + ((p00 + p01) + (p02 + p03)));
        hn1 = ftanh2(base1 + ((p10 + p11) + (p12 + p13)));
    }

    // ---- epilogue ----
    {   // logits(h_TT) both batches -> qp[TT&3] = qp[0]
        float q = wfs * hn0;
        q = DPP_ADD(q, 0xB1); q = DPP_ADD(q, 0x4E);
        q = DPP_ADD(q, 0x124); q = DPP_ADD(q, 0x128);
        float q0 = bcast(q, 0)  + bcast(q, 16);
        float q1 = bcast(q, 32) + bcast(q, 48);
        if (l == 0) qp[0][0][wv] = f32x2{q0, q1};
        float r = wfs * hn1;
        r = DPP_ADD(r, 0xB1); r = DPP_ADD(r, 0x4E);
        r = DPP_ADD(r, 0x124); r = DPP_ADD(r, 0x128);
        float r0 = bcast(r, 0)  + bcast(r, 16);
        float r1 = bcast(r, 32) + bcast(r, 48);
        if (l == 0) qp[0][1][wv] = f32x2{r0, r1};
    }
    __syncthreads();
    if (tid == 0) {
        // out[TT-2] = logits(h_{TT-1}) from qp[3]; out[TT-1] from qp[0]
        f32x2 s = (qp[3][0][0] + qp[3][0][1]) + (qp[3][0][2] + qp[3][0][3]);
        s.x += bf0; s.y += bf1;
        *(f32x2*)(o0 + (TT - 2) * CC) = s;
        f32x2 s2 = (qp[0][0][0] + qp[0][0][1]) + (qp[0][0][2] + qp[0][0][3]);
        s2.x += bf0; s2.y += bf1;
        *(f32x2*)(o0 + (TT - 1) * CC) = s2;
        f32x2 u = (qp[3][1][0] + qp[3][1][1]) + (qp[3][1][2] + qp[3][1][3]);
        u.x += bf0; u.y += bf1;
        *(f32x2*)(o1 + (TT - 2) * CC) = u;
        f32x2 u2 = (qp[0][1][0] + qp[0][1][1]) + (qp[0][1][2] + qp[0][1][3]);
        u2.x += bf0; u2.y += bf1;
        *(f32x2*)(o1 + (TT - 1) * CC) = u2;
    }
    // residual rings: out[1008..1021] live in obuf slots 0..13 (28 floats each)
    if (tid < 28) {
        ((float*)(o0 + 1008 * CC))[tid] = ((const float*)obuf[0])[tid];
    }
    if (tid >= 32 && tid < 60) {
        ((float*)(o1 + 1008 * CC))[tid - 32] = ((const float*)obuf[1])[tid - 32];
    }
}

extern "C" void kernel_launch(void* const* d_in, const int* in_sizes, int n_in,
                              void* d_out, int out_size, void* d_ws, size_t ws_size,
                              hipStream_t stream) {
    const float* x    = (const float*)d_in[0];
    const float* W_ih = (const float*)d_in[1];
    const float* W_hh = (const float*)d_in[2];
    const float* b_ih = (const float*)d_in[3];
    const float* b_hh = (const float*)d_in[4];
    const float* W_fc = (const float*)d_in[5];
    const float* b_fc = (const float*)d_in[6];
    float* out = (float*)d_out;

    rnn_kernel<<<BB, 256, 0, stream>>>(x, W_ih, W_hh, b_ih, b_hh, W_fc, b_fc, out);
}

// Round 17
// 498.076 us; speedup vs baseline: 1.4073x; 1.4073x over previous
//
#include <hip/hip_runtime.h>

typedef float f32x2 __attribute__((ext_vector_type(2)));
typedef float f32x4 __attribute__((ext_vector_type(4)));
typedef _Float16 h16;
typedef h16 f16x8 __attribute__((ext_vector_type(8)));
typedef int int4v __attribute__((ext_vector_type(4)));

#define NB 16          // batches per block
#define BB 16          // blocks: 16 x 16 = 256 batches
#define TT 1024
#define HH 128
#define CC 2
#define XSTR 1028      // xs row stride in floats (banks: 4c spread)
#define LOG2E2 2.885390081777927f

// tanh(u) = 1 - 2/(exp2(u2)+1), u2 = 2*log2e*u (scale folded into W/wih/bias).
__device__ __forceinline__ float ftanh2(float u2) {
    float e = __builtin_amdgcn_exp2f(u2);
    float r = __builtin_amdgcn_rcpf(e + 1.0f);
    return fmaf(-2.0f, r, 1.0f);
}
__device__ __forceinline__ int pkrtz(float a, float b) {   // (lo=a, hi=b) f16 pair
    return __builtin_bit_cast(int, __builtin_amdgcn_cvt_pkrtz(a, b));
}
__device__ __forceinline__ f16x8 mk8(int d0, int d1, int d2, int d3) {
    int4v v = {d0, d1, d2, d3};
    return __builtin_bit_cast(f16x8, v);
}
__device__ __forceinline__ f16x8 pack8(const float* p, float s) {
    f16x8 v;
    #pragma unroll
    for (int j = 0; j < 8; ++j) v[j] = (h16)(p[j] * s);
    return v;
}
// LDS-only barrier (global logit stores need no ordering vs the barrier)
#define SYNC() asm volatile("s_waitcnt lgkmcnt(0)\n\ts_barrier" ::: "memory")
#define MFMA16(a,b,c) __builtin_amdgcn_mfma_f32_16x16x32_f16((a),(b),(c),0,0,0)

// R13: MFMA RNN. H_new[128 x 16batches] = Whh' [128 x 130] * [h; x_t; 1] via
// 16x16x32 f16 MFMA. 5 waves: wv 0-3 own 2 row-tiles each (10 MFMA/step),
// wv 4 computes logits (Wfc padded to M=16, bias via the k=129 column).
// K-mapping note: MFMA pairs A/B POSITIONALLY, so any k<->(laneq,elem)
// bijection is correct as long as A-pack and B-pack agree (we use k=q*8+j).
// C/D layout is the verified one: col=lane&15, row=(lane>>4)*4+reg.
// h crosses steps through a double-buffered packed-f16 LDS buffer
// [m][pair][q][c] stride-17; one lgkm-only barrier per step.
__global__ __launch_bounds__(320, 1) void rnn_kernel(
    const float* __restrict__ x, const float* __restrict__ W_ih,
    const float* __restrict__ W_hh, const float* __restrict__ b_ih,
    const float* __restrict__ b_hh, const float* __restrict__ W_fc,
    const float* __restrict__ b_fc, float* __restrict__ out)
{
    const int tid = threadIdx.x;        // 0..319
    const int wv  = tid >> 6;           // wave 0..4
    const int l   = tid & 63;
    const int c   = l & 15;             // batch column
    const int q   = l >> 4;             // k-group / row-group
    const int b0  = blockIdx.x * NB;

    __shared__ float xs[NB * XSTR];     // 16 x-rows
    __shared__ int   hb[2][1088];       // packed-f16 h, double buffered
                                        // idx = (m*2+pair)*68 + q*17 + c

    // ---- preload x (coalesced f32x4), zero h_{-1} buffer ----
    #pragma unroll
    for (int i = 0; i < 13; ++i) {
        int idx = tid + i * 320;        // 4096 vec4 total
        if (idx < 4096) {
            int row = idx >> 8, c4 = idx & 255;
            ((f32x4*)(xs + row * XSTR))[c4] =
                ((const f32x4*)(x + (size_t)(b0 + row) * TT))[c4];
        }
    }
    for (int i = tid; i < 1088; i += 320) hb[0][i] = 0;

    // ---- A-fragments (loop-invariant; lane: row=(l&15), k=kt*32+q*8+j) ----
    f16x8 af[2][5];   // main waves: W_hh rows, + kt4 = [wih | bias] columns
    f16x8 lf[5];      // logit wave: W_fc rows 0..1 (pad M=16), + kt4 = [0 | bfc]
    if (wv < 4) {
        #pragma unroll
        for (int i = 0; i < 2; ++i) {
            int r = (2 * wv + i) * 16 + c;
            const float* wr = W_hh + (size_t)r * HH + q * 8;
            #pragma unroll
            for (int kt = 0; kt < 4; ++kt)
                af[i][kt] = pack8(wr + kt * 32, LOG2E2);
            int d0 = (q == 0)
                ? pkrtz(W_ih[r] * LOG2E2, (b_ih[r] + b_hh[r]) * LOG2E2) : 0;
            af[i][4] = mk8(d0, 0, 0, 0);
        }
    } else {
        #pragma unroll
        for (int kt = 0; kt < 4; ++kt)
            lf[kt] = (c < 2) ? pack8(W_fc + c * HH + kt * 32 + q * 8, 1.0f)
                             : mk8(0, 0, 0, 0);
        lf[4] = mk8((q == 0 && c < 2) ? pkrtz(0.f, b_fc[c]) : 0, 0, 0, 0);
    }

    // B-read offsets: element j of lane (c,q) at kt = h[kt*32+q*8+j]
    const int offA = ((q & 1) * 2) * 17 + c;
    const int offB = offA + 17;
    const int mrow = q >> 1;
    float* oc = out + (size_t)(b0 + c) * TT * CC;

    __syncthreads();                    // xs + hb[0] visible

    #pragma unroll 2
    for (int t = 0; t < TT; ++t) {
        const int* hr = hb[t & 1];      // h_{t-1}
        int* hw = hb[(t + 1) & 1];      // h_t destination

        f16x8 bf[5];
        #pragma unroll
        for (int kt = 0; kt < 4; ++kt) {
            const int mb = (2 * kt + mrow) * 136;
            bf[kt] = mk8(hr[mb + offA], hr[mb + 68 + offA],
                         hr[mb + offB], hr[mb + 68 + offB]);
        }

        if (wv < 4) {
            float xc = xs[c * XSTR + t];
            bf[4] = mk8((q == 0) ? pkrtz(xc, 1.0f) : 0, 0, 0, 0);

            f32x4 a0 = {0.f, 0.f, 0.f, 0.f}, a1 = a0;
            #pragma unroll
            for (int kt = 0; kt < 5; ++kt) {
                a0 = MFMA16(af[0][kt], bf[kt], a0);
                a1 = MFMA16(af[1][kt], bf[kt], a1);
            }
            // D is already u2 = LOG2E2 * preactivation (bias/x folded in)
            float h00 = ftanh2(a0.x), h01 = ftanh2(a0.y);
            float h02 = ftanh2(a0.z), h03 = ftanh2(a0.w);
            float h10 = ftanh2(a1.x), h11 = ftanh2(a1.y);
            float h12 = ftanh2(a1.z), h13 = ftanh2(a1.w);
            const int base = q * 17 + c;
            const int w0 = (2 * wv) * 136 + base;
            const int w1 = (2 * wv + 1) * 136 + base;
            hw[w0]      = pkrtz(h00, h01);
            hw[w0 + 68] = pkrtz(h02, h03);
            hw[w1]      = pkrtz(h10, h11);
            hw[w1 + 68] = pkrtz(h12, h13);
        } else {
            // logits of h_{t-1}; B kt4 = (x=0, 1) -> x*0 + 1*bfc
            bf[4] = mk8((q == 0) ? 0x3C000000 : 0, 0, 0, 0);
            f32x4 la = {0.f, 0.f, 0.f, 0.f};
            #pragma unroll
            for (int kt = 0; kt < 5; ++kt)
                la = MFMA16(lf[kt], bf[kt], la);
            if (t >= 1 && q == 0)
                *(f32x2*)(oc + (size_t)(t - 1) * CC) = f32x2{la.x, la.y};
        }
        SYNC();                         // h_t visible; reads of hr drained
    }

    // ---- epilogue: logits of h_{TT-1} (in hb[0]) ----
    if (wv == 4) {
        const int* hr = hb[0];
        f16x8 bf[5];
        #pragma unroll
        for (int kt = 0; kt < 4; ++kt) {
            const int mb = (2 * kt + mrow) * 136;
            bf[kt] = mk8(hr[mb + offA], hr[mb + 68 + offA],
                         hr[mb + offB], hr[mb + 68 + offB]);
        }
        bf[4] = mk8((q == 0) ? 0x3C000000 : 0, 0, 0, 0);
        f32x4 la = {0.f, 0.f, 0.f, 0.f};
        #pragma unroll
        for (int kt = 0; kt < 5; ++kt)
            la = MFMA16(lf[kt], bf[kt], la);
        if (q == 0)
            *(f32x2*)(oc + (size_t)(TT - 1) * CC) = f32x2{la.x, la.y};
    }
}

extern "C" void kernel_launch(void* const* d_in, const int* in_sizes, int n_in,
                              void* d_out, int out_size, void* d_ws, size_t ws_size,
                              hipStream_t stream) {
    const float* x    = (const float*)d_in[0];
    const float* W_ih = (const float*)d_in[1];
    const float* W_hh = (const float*)d_in[2];
    const float* b_ih = (const float*)d_in[3];
    const float* b_hh = (const float*)d_in[4];
    const float* W_fc = (const float*)d_in[5];
    const float* b_fc = (const float*)d_in[6];
    float* out = (float*)d_out;

    rnn_kernel<<<BB, 320, 0, stream>>>(x, W_ih, W_hh, b_ih, b_hh, W_fc, b_fc, out);
}